// Round 19
// baseline (120.129 us; speedup 1.0000x reference)
//
#include <hip/hip_runtime.h>
#include <hip/hip_fp16.h>

#define NN 8192
#define KDIM 256
#define FDIM 64
#define CBLK 512            // cols per segment
#define NSEG (NN / CBLK)    // 16 segments
#define WPB  (CBLK / 32)    // 16 windows per segment
#define ITER 4              // row-groups per block (64 rows total)

typedef __attribute__((ext_vector_type(8))) _Float16 f16x8;
typedef __attribute__((ext_vector_type(4))) float f32x4;
typedef __attribute__((ext_vector_type(4))) int i32x4;
typedef __attribute__((ext_vector_type(4))) unsigned u32x4;

union H2U { __half2 h; unsigned u; };
union HU  { __half h; unsigned short u; };

__device__ __forceinline__ unsigned h2u(__half2 h) { H2U x; x.h = h; return x.u; }

__device__ __forceinline__ unsigned pkmul(unsigned a, unsigned b) {
    unsigned d; asm("v_pk_mul_f16 %0, %1, %2" : "=v"(d) : "v"(a), "v"(b)); return d;
}
__device__ __forceinline__ unsigned pkmax(unsigned a, unsigned b) {
    unsigned d; asm("v_pk_max_f16 %0, %1, %2" : "=v"(d) : "v"(a), "v"(b)); return d;
}

__device__ __forceinline__ float wred64(float v) {
    v += __shfl_xor(v, 1);
    v += __shfl_xor(v, 2);
    v += __shfl_xor(v, 4);
    v += __shfl_xor(v, 8);
    v += __shfl_xor(v, 16);
    v += __shfl_xor(v, 32);
    return v;
}

// Phase 1: Wh = h@W (f32 accum); emit Wh^T in MFMA-fragment order as fp16.
__global__ __launch_bounds__(256) void gat_phase1(
    const float* __restrict__ h, const float* __restrict__ W,
    const float* __restrict__ a, unsigned short* __restrict__ wfrag,
    float* __restrict__ fi, float* __restrict__ fj)
{
    __shared__ unsigned short wht_s[FDIM][20];
    const int tid = threadIdx.x;
    const int f  = tid & 63;
    const int rg = tid >> 6;
    const int i0 = blockIdx.x << 4;

    const float* __restrict__ h0 = h + (size_t)(i0 + rg * 4) * KDIM;
    const float* __restrict__ h1 = h0 + KDIM;
    const float* __restrict__ h2 = h0 + 2 * KDIM;
    const float* __restrict__ h3 = h0 + 3 * KDIM;

    float acc0 = 0.f, acc1 = 0.f, acc2 = 0.f, acc3 = 0.f;
    #pragma unroll 4
    for (int k4 = 0; k4 < KDIM / 4; ++k4) {
        const float4 r0 = *(const float4*)(h0 + k4 * 4);
        const float4 r1 = *(const float4*)(h1 + k4 * 4);
        const float4 r2 = *(const float4*)(h2 + k4 * 4);
        const float4 r3 = *(const float4*)(h3 + k4 * 4);
        const float w0 = W[(k4 * 4 + 0) * FDIM + f];
        const float w1 = W[(k4 * 4 + 1) * FDIM + f];
        const float w2 = W[(k4 * 4 + 2) * FDIM + f];
        const float w3 = W[(k4 * 4 + 3) * FDIM + f];
        acc0 += r0.x * w0 + r0.y * w1 + r0.z * w2 + r0.w * w3;
        acc1 += r1.x * w0 + r1.y * w1 + r1.z * w2 + r1.w * w3;
        acc2 += r2.x * w0 + r2.y * w1 + r2.z * w2 + r2.w * w3;
        acc3 += r3.x * w0 + r3.y * w1 + r3.z * w2 + r3.w * w3;
    }

    HU c0; c0.h = __float2half(acc0);
    HU c1; c1.h = __float2half(acc1);
    HU c2; c2.h = __float2half(acc2);
    HU c3; c3.h = __float2half(acc3);
    const int r0i = rg * 4;
    wht_s[f][r0i + 0] = c0.u;
    wht_s[f][r0i + 1] = c1.u;
    wht_s[f][r0i + 2] = c2.u;
    wht_s[f][r0i + 3] = c3.u;

    const float aL = a[f];
    const float aR = a[FDIM + f];
    float s;
    s = wred64(acc0 * aL); if (f == 0) fi[i0 + r0i + 0] = s;
    s = wred64(acc1 * aL); if (f == 0) fi[i0 + r0i + 1] = s;
    s = wred64(acc2 * aL); if (f == 0) fi[i0 + r0i + 2] = s;
    s = wred64(acc3 * aL); if (f == 0) fi[i0 + r0i + 3] = s;
    s = wred64(acc0 * aR); if (f == 0) fj[i0 + r0i + 0] = s;
    s = wred64(acc1 * aR); if (f == 0) fj[i0 + r0i + 1] = s;
    s = wred64(acc2 * aR); if (f == 0) fj[i0 + r0i + 2] = s;
    s = wred64(acc3 * aR); if (f == 0) fj[i0 + r0i + 3] = s;

    __syncthreads();
    if (tid < 128) {
        const int li2 = tid & 15;
        const int q2  = (tid >> 4) & 1;
        const int b   = tid >> 5;
        const int t   = i0 >> 5;
        const int hh  = (i0 >> 4) & 1;
        const int feat = b * 16 + li2;
        const ushort4 lo = *(const ushort4*)&wht_s[feat][q2 * 8];
        const ushort4 hi = *(const ushort4*)&wht_s[feat][q2 * 8 + 4];
        const int lg = (hh * 2 + q2) * 16 + li2;
        unsigned short* dst = wfrag + (size_t)t * 2048 + b * 512 + lg * 8;
        *(ushort4*)(dst)     = lo;
        *(ushort4*)(dst + 4) = hi;
    }
}

// Fused, dual-queue pipelined: block = 64 rows x 512-col segment, 4 iters of
// 16 rows. wfrag slice + E tables staged to LDS ONCE -> compute phase is
// 100% LDS (lgkmcnt). adj prefetch for iter g+1 stays in the vmcnt queue,
// untouched by compute(g)'s waits -> true stage/compute overlap in-block.
__global__ __launch_bounds__(256, 2) void gat_fused(
    const int* __restrict__ adj, const unsigned short* __restrict__ wfrag,
    const float* __restrict__ fi, const float* __restrict__ fjg,
    float* __restrict__ vpart, float* __restrict__ zpart)
{
    __shared__ unsigned short wfl[WPB * 2048];   // 64 KB B-fragment slice
    __shared__ unsigned Ebuf[512];               // E1[0..255] E2[256..511] (2 KB)
    __shared__ unsigned mask_lds[2][16][17];     // dbuf bit-mask (2.2 KB)
    __shared__ float red[2 * 16 * 64];           // 8 KB
    __shared__ float zred[4][16];

    const int tid = threadIdx.x;
    const int w  = tid >> 6;   // 0..3
    const int l  = tid & 63;
    const int li = l & 15;
    const int q  = l >> 4;
    const int qo = q * 8;
    const int bid = blockIdx.x;
    const int seg = bid >> 7;            // 16 segs x 128 row-blocks
    const int rb  = bid & 127;           // rows rb*64 .. rb*64+63

    // ---- one-time LDS staging: wfrag slice + E tables ----
    {
        const u32x4* src = (const u32x4*)(wfrag + (size_t)seg * WPB * 2048);
        u32x4* dst = (u32x4*)wfl;
        for (int t = tid; t < WPB * 2048 / 8; t += 256)
            dst[t] = src[t];
        const float2 f2 = ((const float2*)fjg)[seg * 256 + tid];
        Ebuf[tid]       = h2u(__floats2half2_rn(__expf(f2.x), __expf(f2.y)));
        Ebuf[256 + tid] = h2u(__floats2half2_rn(__expf(0.2f * f2.x), __expf(0.2f * f2.y)));
    }

    const int wsel = (l & 7) * 4;
    i32x4 v[8];

    // LOADADJ(g): wave w loads rows 4w..4w+3 of group g (2 int4/row)
    #define LOADADJ(g)                                                        \
        do {                                                                  \
            _Pragma("unroll")                                                 \
            for (int r = 0; r < 4; ++r) {                                     \
                const i32x4* rowp = (const i32x4*)(adj +                      \
                    (size_t)(rb * 64 + (g) * 16 + 4 * w + r) * NN + seg * CBLK); \
                v[r * 2 + 0] = rowp[l];                                       \
                v[r * 2 + 1] = rowp[64 + l];                                  \
            }                                                                 \
        } while (0)

    #define BALLOT(g)                                                         \
        do {                                                                  \
            _Pragma("unroll")                                                 \
            for (int r = 0; r < 4; ++r)                                       \
            for (int j = 0; j < 2; ++j) {                                     \
                const i32x4 x = v[r * 2 + j];                                 \
                unsigned nib = (unsigned)(x[0] > 0) | ((unsigned)(x[1] > 0) << 1) \
                             | ((unsigned)(x[2] > 0) << 2) | ((unsigned)(x[3] > 0) << 3); \
                unsigned p = nib << wsel;                                     \
                p |= __shfl_xor(p, 1);                                        \
                p |= __shfl_xor(p, 2);                                        \
                p |= __shfl_xor(p, 4);                                        \
                if ((l & 7) == 0)                                             \
                    mask_lds[(g) & 1][4 * w + r][j * 8 + (l >> 3)] = p;       \
            }                                                                 \
        } while (0)

    // prologue: stage group 0's mask, issue group 1's adj
    LOADADJ(0);
    BALLOT(0);
    LOADADJ(1);
    __syncthreads();   // wfl + Ebuf + mask[0] visible

    const unsigned* E1p = Ebuf;
    const unsigned* E2p = Ebuf + 256;
    const f16x8 ones = { (_Float16)1.f, (_Float16)1.f, (_Float16)1.f, (_Float16)1.f,
                         (_Float16)1.f, (_Float16)1.f, (_Float16)1.f, (_Float16)1.f };

    for (int g = 0; g < ITER; ++g) {
        const int i0 = rb * 64 + g * 16;
        const float fiv = fi[i0 + li];
        const unsigned e1i2 = h2u(__floats2half2_rn(__expf(fiv), __expf(fiv)));
        const unsigned e2i2 = h2u(__floats2half2_rn(__expf(0.2f * fiv), __expf(0.2f * fiv)));

        f32x4 acc0 = {0.f, 0.f, 0.f, 0.f};
        f32x4 acc1 = {0.f, 0.f, 0.f, 0.f};
        f32x4 acc2 = {0.f, 0.f, 0.f, 0.f};
        f32x4 acc3 = {0.f, 0.f, 0.f, 0.f};
        f32x4 accz = {0.f, 0.f, 0.f, 0.f};

        // compute group g: LDS-only reads (lgkmcnt) -> adj(g+1) stays in flight
        #pragma unroll
        for (int s = 0; s < WPB / 4; ++s) {
            const int tw = w + 4 * s;
            const unsigned mq8 = (mask_lds[g & 1][li][tw] >> qo) & 0xFFu;
            const int ep = tw * 16 + q * 4;
            const uint4 e1w = *(const uint4*)(E1p + ep);
            const uint4 e2w = *(const uint4*)(E2p + ep);
            const unsigned short* wt = wfl + tw * 2048 + l * 8;
            const f16x8 b0 = *(const f16x8*)(wt);
            const f16x8 b1 = *(const f16x8*)(wt + 512);
            const f16x8 b2 = *(const f16x8*)(wt + 1024);
            const f16x8 b3 = *(const f16x8*)(wt + 1536);

            const unsigned mm0 = ((mq8 &   1u) ? 0x0000FFFFu : 0u) | ((mq8 &   2u) ? 0xFFFF0000u : 0u);
            const unsigned mm1 = ((mq8 &   4u) ? 0x0000FFFFu : 0u) | ((mq8 &   8u) ? 0xFFFF0000u : 0u);
            const unsigned mm2 = ((mq8 &  16u) ? 0x0000FFFFu : 0u) | ((mq8 &  32u) ? 0xFFFF0000u : 0u);
            const unsigned mm3 = ((mq8 &  64u) ? 0x0000FFFFu : 0u) | ((mq8 & 128u) ? 0xFFFF0000u : 0u);

            union { unsigned u[4]; f16x8 vv; } af;
            af.u[0] = pkmax(pkmul(e1i2, e1w.x), pkmul(e2i2, e2w.x)) & mm0;
            af.u[1] = pkmax(pkmul(e1i2, e1w.y), pkmul(e2i2, e2w.y)) & mm1;
            af.u[2] = pkmax(pkmul(e1i2, e1w.z), pkmul(e2i2, e2w.z)) & mm2;
            af.u[3] = pkmax(pkmul(e1i2, e1w.w), pkmul(e2i2, e2w.w)) & mm3;

            acc0 = __builtin_amdgcn_mfma_f32_16x16x32_f16(af.vv, b0, acc0, 0, 0, 0);
            acc1 = __builtin_amdgcn_mfma_f32_16x16x32_f16(af.vv, b1, acc1, 0, 0, 0);
            acc2 = __builtin_amdgcn_mfma_f32_16x16x32_f16(af.vv, b2, acc2, 0, 0, 0);
            acc3 = __builtin_amdgcn_mfma_f32_16x16x32_f16(af.vv, b3, acc3, 0, 0, 0);
            accz = __builtin_amdgcn_mfma_f32_16x16x32_f16(af.vv, ones, accz, 0, 0, 0);
        }

        // ballot next group's mask (waits vmcnt for v), issue group g+2's adj
        if (g + 1 < ITER) BALLOT(g + 1);
        if (g + 2 < ITER) LOADADJ(g + 2);

        // epilogue: 2-round cross-wave reduce + segment partials
        if (li == 0) {
            #pragma unroll
            for (int r = 0; r < 4; ++r) zred[w][q * 4 + r] = accz[r];
        }
        if (w < 2) {
            #pragma unroll
            for (int r = 0; r < 4; ++r) {
                red[(w * 16 + q * 4 + r) * 64 + 0 * 16 + li] = acc0[r];
                red[(w * 16 + q * 4 + r) * 64 + 1 * 16 + li] = acc1[r];
                red[(w * 16 + q * 4 + r) * 64 + 2 * 16 + li] = acc2[r];
                red[(w * 16 + q * 4 + r) * 64 + 3 * 16 + li] = acc3[r];
            }
        }
        __syncthreads();
        if (w >= 2) {
            #pragma unroll
            for (int r = 0; r < 4; ++r) {
                red[((w - 2) * 16 + q * 4 + r) * 64 + 0 * 16 + li] += acc0[r];
                red[((w - 2) * 16 + q * 4 + r) * 64 + 1 * 16 + li] += acc1[r];
                red[((w - 2) * 16 + q * 4 + r) * 64 + 2 * 16 + li] += acc2[r];
                red[((w - 2) * 16 + q * 4 + r) * 64 + 3 * 16 + li] += acc3[r];
            }
        }
        __syncthreads();
        {
            const int f  = tid & 63;
            const int ig = tid >> 6;   // 0..3
            #pragma unroll
            for (int cc = 0; cc < 4; ++cc) {
                const int i = cc * 4 + ig;
                const float vv = red[(0 * 16 + i) * 64 + f] + red[(1 * 16 + i) * 64 + f];
                vpart[(size_t)(seg * NN + i0 + i) * FDIM + f] = vv;
                if (f == 0) {
                    const float zz = (zred[0][i] + zred[1][i]) + (zred[2][i] + zred[3][i]);
                    zpart[seg * NN + i0 + i] = zz;
                }
            }
        }
        __syncthreads();   // red/zred free for next iteration; mask[g+1] visible
    }
    #undef LOADADJ
    #undef BALLOT
}

// Merge 16 segment partials: out = (sum v)/(sum z). 131072 float4.
__global__ __launch_bounds__(256) void gat_merge(
    const float* __restrict__ vpart, const float* __restrict__ zpart,
    float* __restrict__ out)
{
    const int g = blockIdx.x * 256 + threadIdx.x;
    const int row = g >> 4;
    float4 v = ((const float4*)vpart)[g];
    float z = zpart[row];
    #pragma unroll
    for (int k = 1; k < NSEG; ++k) {
        const float4 b = ((const float4*)vpart)[g + (size_t)k * NN * (FDIM / 4)];
        v.x += b.x; v.y += b.y; v.z += b.z; v.w += b.w;
        z += zpart[row + k * NN];
    }
    float4 o;
    o.x = v.x / z; o.y = v.y / z; o.z = v.z / z; o.w = v.w / z;
    ((float4*)out)[g] = o;
}

extern "C" void kernel_launch(void* const* d_in, const int* in_sizes, int n_in,
                              void* d_out, int out_size, void* d_ws, size_t ws_size,
                              hipStream_t stream) {
    const float* h   = (const float*)d_in[0];
    const int*   adj = (const int*)d_in[1];
    const float* W   = (const float*)d_in[2];
    const float* a   = (const float*)d_in[3];
    float* out = (float*)d_out;

    // ws: wfrag 1MB | fi 32K | fj 32K | vpart 32MB @2MB | zpart 512K @34MB  (ws >= 66MB proven)
    unsigned short* wfrag = (unsigned short*)d_ws;
    float* fi = (float*)((char*)d_ws + (size_t)NN * FDIM * 2);
    float* fj = fi + NN;
    float* vpart = (float*)((char*)d_ws + (2u << 20));
    float* zpart = (float*)((char*)d_ws + (34u << 20));

    gat_phase1<<<NN / 16, 256, 0, stream>>>(h, W, a, wfrag, fi, fj);
    gat_fused<<<NSEG * 128, 256, 0, stream>>>(adj, wfrag, fi, fj, vpart, zpart);
    gat_merge<<<NN * FDIM / 1024, 256, 0, stream>>>(vpart, zpart, out);
}

// Round 20
// 92.120 us; speedup vs baseline: 1.3041x; 1.3041x over previous
//
#include <hip/hip_runtime.h>
#include <hip/hip_fp16.h>

#define NN 8192
#define KDIM 256
#define FDIM 64
#define CBLK 1024          // cols per fused block
#define NSEG (NN / CBLK)   // 8 column segments

typedef __attribute__((ext_vector_type(8))) _Float16 f16x8;
typedef __attribute__((ext_vector_type(4))) float f32x4;
typedef __attribute__((ext_vector_type(4))) int i32x4;

union H2U { __half2 h; unsigned u; };
union HU  { __half h; unsigned short u; };

__device__ __forceinline__ unsigned h2u(__half2 h) { H2U x; x.h = h; return x.u; }

__device__ __forceinline__ unsigned pkmul(unsigned a, unsigned b) {
    unsigned d; asm("v_pk_mul_f16 %0, %1, %2" : "=v"(d) : "v"(a), "v"(b)); return d;
}
__device__ __forceinline__ unsigned pkmax(unsigned a, unsigned b) {
    unsigned d; asm("v_pk_max_f16 %0, %1, %2" : "=v"(d) : "v"(a), "v"(b)); return d;
}

__device__ __forceinline__ float wred64(float v) {
    v += __shfl_xor(v, 1);
    v += __shfl_xor(v, 2);
    v += __shfl_xor(v, 4);
    v += __shfl_xor(v, 8);
    v += __shfl_xor(v, 16);
    v += __shfl_xor(v, 32);
    return v;
}

// Phase 1: Wh = h@W (f32 accum); emit Wh^T in MFMA-fragment order as fp16.
__global__ __launch_bounds__(256) void gat_phase1(
    const float* __restrict__ h, const float* __restrict__ W,
    const float* __restrict__ a, unsigned short* __restrict__ wfrag,
    float* __restrict__ fi, float* __restrict__ fj)
{
    __shared__ unsigned short wht_s[FDIM][20];
    const int tid = threadIdx.x;
    const int f  = tid & 63;
    const int rg = tid >> 6;
    const int i0 = blockIdx.x << 4;

    const float* __restrict__ h0 = h + (size_t)(i0 + rg * 4) * KDIM;
    const float* __restrict__ h1 = h0 + KDIM;
    const float* __restrict__ h2 = h0 + 2 * KDIM;
    const float* __restrict__ h3 = h0 + 3 * KDIM;

    float acc0 = 0.f, acc1 = 0.f, acc2 = 0.f, acc3 = 0.f;
    #pragma unroll 4
    for (int k4 = 0; k4 < KDIM / 4; ++k4) {
        const float4 r0 = *(const float4*)(h0 + k4 * 4);
        const float4 r1 = *(const float4*)(h1 + k4 * 4);
        const float4 r2 = *(const float4*)(h2 + k4 * 4);
        const float4 r3 = *(const float4*)(h3 + k4 * 4);
        const float w0 = W[(k4 * 4 + 0) * FDIM + f];
        const float w1 = W[(k4 * 4 + 1) * FDIM + f];
        const float w2 = W[(k4 * 4 + 2) * FDIM + f];
        const float w3 = W[(k4 * 4 + 3) * FDIM + f];
        acc0 += r0.x * w0 + r0.y * w1 + r0.z * w2 + r0.w * w3;
        acc1 += r1.x * w0 + r1.y * w1 + r1.z * w2 + r1.w * w3;
        acc2 += r2.x * w0 + r2.y * w1 + r2.z * w2 + r2.w * w3;
        acc3 += r3.x * w0 + r3.y * w1 + r3.z * w2 + r3.w * w3;
    }

    HU c0; c0.h = __float2half(acc0);
    HU c1; c1.h = __float2half(acc1);
    HU c2; c2.h = __float2half(acc2);
    HU c3; c3.h = __float2half(acc3);
    const int r0i = rg * 4;
    wht_s[f][r0i + 0] = c0.u;
    wht_s[f][r0i + 1] = c1.u;
    wht_s[f][r0i + 2] = c2.u;
    wht_s[f][r0i + 3] = c3.u;

    const float aL = a[f];
    const float aR = a[FDIM + f];
    float s;
    s = wred64(acc0 * aL); if (f == 0) fi[i0 + r0i + 0] = s;
    s = wred64(acc1 * aL); if (f == 0) fi[i0 + r0i + 1] = s;
    s = wred64(acc2 * aL); if (f == 0) fi[i0 + r0i + 2] = s;
    s = wred64(acc3 * aL); if (f == 0) fi[i0 + r0i + 3] = s;
    s = wred64(acc0 * aR); if (f == 0) fj[i0 + r0i + 0] = s;
    s = wred64(acc1 * aR); if (f == 0) fj[i0 + r0i + 1] = s;
    s = wred64(acc2 * aR); if (f == 0) fj[i0 + r0i + 2] = s;
    s = wred64(acc3 * aR); if (f == 0) fj[i0 + r0i + 3] = s;

    __syncthreads();
    if (tid < 128) {
        const int li2 = tid & 15;
        const int q2  = (tid >> 4) & 1;
        const int b   = tid >> 5;
        const int t   = i0 >> 5;
        const int hh  = (i0 >> 4) & 1;
        const int feat = b * 16 + li2;
        const ushort4 lo = *(const ushort4*)&wht_s[feat][q2 * 8];
        const ushort4 hi = *(const ushort4*)&wht_s[feat][q2 * 8 + 4];
        const int lg = (hh * 2 + q2) * 16 + li2;
        unsigned short* dst = wfrag + (size_t)t * 2048 + b * 512 + lg * 8;
        *(ushort4*)(dst)     = lo;
        *(ushort4*)(dst + 4) = hi;
    }
}

// Fused, fine-grained: block = 16 rows x 1024 cols (segment seg). 256 thr /
// 4 waves. Phase-serial inside (R12-proven); plain adj loads (R16-proven).
__global__ __launch_bounds__(256, 4) void gat_fused(
    const int* __restrict__ adj, const unsigned short* __restrict__ wfrag,
    const float* __restrict__ fi, const float* __restrict__ fjg,
    float* __restrict__ vpart, float* __restrict__ zpart)
{
    __shared__ unsigned mask_lds[16][33];   // bit-mask for 16 rows x 1024 cols
    __shared__ unsigned Ebuf[1024];         // E1[0..511] E2[512..1023]
    __shared__ float red[2 * 16 * 64];      // 8 KB cross-wave reduce
    __shared__ float zred[4][16];

    const int tid = threadIdx.x;
    const int w  = tid >> 6;   // 0..3
    const int l  = tid & 63;
    const int li = l & 15;
    const int q  = l >> 4;
    const int qo = q * 8;
    const int bid = blockIdx.x;
    const int seg = bid & (NSEG - 1);
    const int i0  = (bid / NSEG) << 4;

    // ---- E tables for this segment's fj (512 pairs) ----
    unsigned* E1p = Ebuf;
    unsigned* E2p = Ebuf + 512;
    for (int t = tid; t < 512; t += 256) {
        const float2 f2 = ((const float2*)fjg)[seg * 512 + t];
        E1p[t] = h2u(__floats2half2_rn(__expf(f2.x), __expf(f2.y)));
        E2p[t] = h2u(__floats2half2_rn(__expf(0.2f * f2.x), __expf(0.2f * f2.y)));
    }

    // ---- stage adj segment -> LDS bit-mask (wave w: rows 4w..4w+3) ----
    const int wsel = (l & 7) * 4;
    #pragma unroll
    for (int rp = 0; rp < 2; ++rp) {
        const int r0 = 4 * w + 2 * rp;
        const i32x4* __restrict__ p0 =
            (const i32x4*)(adj + (size_t)(i0 + r0) * NN + seg * CBLK);
        const i32x4* __restrict__ p1 = p0 + (NN / 4);
        i32x4 v[8];
        #pragma unroll
        for (int k = 0; k < 4; ++k) v[k]     = p0[k * 64 + l];
        #pragma unroll
        for (int k = 0; k < 4; ++k) v[4 + k] = p1[k * 64 + l];
        #pragma unroll
        for (int k = 0; k < 8; ++k) {
            const i32x4 x = v[k];
            unsigned nib = (unsigned)(x[0] > 0) | ((unsigned)(x[1] > 0) << 1)
                         | ((unsigned)(x[2] > 0) << 2) | ((unsigned)(x[3] > 0) << 3);
            unsigned p = nib << wsel;
            p |= __shfl_xor(p, 1);
            p |= __shfl_xor(p, 2);
            p |= __shfl_xor(p, 4);
            const int rr = r0 + (k >> 2);       // k<4 -> row r0, k>=4 -> r0+1
            if ((l & 7) == 0) mask_lds[rr][(k & 3) * 8 + (l >> 3)] = p;
        }
    }

    const float fiv = fi[i0 + li];
    const unsigned e1i2 = h2u(__floats2half2_rn(__expf(fiv), __expf(fiv)));
    const unsigned e2i2 = h2u(__floats2half2_rn(__expf(0.2f * fiv), __expf(0.2f * fiv)));
    const unsigned short* __restrict__ wf =
        wfrag + (size_t)(seg * 32) * 2048 + l * 8;

    __syncthreads();

    f32x4 acc0 = {0.f, 0.f, 0.f, 0.f};
    f32x4 acc1 = {0.f, 0.f, 0.f, 0.f};
    f32x4 acc2 = {0.f, 0.f, 0.f, 0.f};
    f32x4 acc3 = {0.f, 0.f, 0.f, 0.f};
    f32x4 accz = {0.f, 0.f, 0.f, 0.f};
    const f16x8 ones = { (_Float16)1.f, (_Float16)1.f, (_Float16)1.f, (_Float16)1.f,
                         (_Float16)1.f, (_Float16)1.f, (_Float16)1.f, (_Float16)1.f };

    // wave w: windows tw = w + 4s, s in [0,8); 32 windows per block
    #pragma unroll 4
    for (int s = 0; s < 8; ++s) {
        const int tw = w + 4 * s;
        const unsigned mword = mask_lds[li][tw];
        const unsigned mq8 = (mword >> qo) & 0xFFu;
        const int ep = tw * 16 + q * 4;
        const uint4 e1w = *(const uint4*)(E1p + ep);
        const uint4 e2w = *(const uint4*)(E2p + ep);
        const unsigned short* wt = wf + (size_t)tw * 2048;
        const f16x8 b0 = *(const f16x8*)(wt);
        const f16x8 b1 = *(const f16x8*)(wt + 512);
        const f16x8 b2 = *(const f16x8*)(wt + 1024);
        const f16x8 b3 = *(const f16x8*)(wt + 1536);

        const unsigned mm0 = ((mq8 &   1u) ? 0x0000FFFFu : 0u) | ((mq8 &   2u) ? 0xFFFF0000u : 0u);
        const unsigned mm1 = ((mq8 &   4u) ? 0x0000FFFFu : 0u) | ((mq8 &   8u) ? 0xFFFF0000u : 0u);
        const unsigned mm2 = ((mq8 &  16u) ? 0x0000FFFFu : 0u) | ((mq8 &  32u) ? 0xFFFF0000u : 0u);
        const unsigned mm3 = ((mq8 &  64u) ? 0x0000FFFFu : 0u) | ((mq8 & 128u) ? 0xFFFF0000u : 0u);

        union { unsigned u[4]; f16x8 v; } af;
        af.u[0] = pkmax(pkmul(e1i2, e1w.x), pkmul(e2i2, e2w.x)) & mm0;
        af.u[1] = pkmax(pkmul(e1i2, e1w.y), pkmul(e2i2, e2w.y)) & mm1;
        af.u[2] = pkmax(pkmul(e1i2, e1w.z), pkmul(e2i2, e2w.z)) & mm2;
        af.u[3] = pkmax(pkmul(e1i2, e1w.w), pkmul(e2i2, e2w.w)) & mm3;

        acc0 = __builtin_amdgcn_mfma_f32_16x16x32_f16(af.v, b0, acc0, 0, 0, 0);
        acc1 = __builtin_amdgcn_mfma_f32_16x16x32_f16(af.v, b1, acc1, 0, 0, 0);
        acc2 = __builtin_amdgcn_mfma_f32_16x16x32_f16(af.v, b2, acc2, 0, 0, 0);
        acc3 = __builtin_amdgcn_mfma_f32_16x16x32_f16(af.v, b3, acc3, 0, 0, 0);
        accz = __builtin_amdgcn_mfma_f32_16x16x32_f16(af.v, ones, accz, 0, 0, 0);
    }

    // ---- epilogue: 2-round cross-wave reduce, then segment partials ----
    if (li == 0) {
        #pragma unroll
        for (int r = 0; r < 4; ++r)
            zred[w][q * 4 + r] = accz[r];
    }
    if (w < 2) {
        #pragma unroll
        for (int r = 0; r < 4; ++r) {
            red[(w * 16 + q * 4 + r) * 64 + 0 * 16 + li] = acc0[r];
            red[(w * 16 + q * 4 + r) * 64 + 1 * 16 + li] = acc1[r];
            red[(w * 16 + q * 4 + r) * 64 + 2 * 16 + li] = acc2[r];
            red[(w * 16 + q * 4 + r) * 64 + 3 * 16 + li] = acc3[r];
        }
    }
    __syncthreads();
    if (w >= 2) {
        #pragma unroll
        for (int r = 0; r < 4; ++r) {
            red[((w - 2) * 16 + q * 4 + r) * 64 + 0 * 16 + li] += acc0[r];
            red[((w - 2) * 16 + q * 4 + r) * 64 + 1 * 16 + li] += acc1[r];
            red[((w - 2) * 16 + q * 4 + r) * 64 + 2 * 16 + li] += acc2[r];
            red[((w - 2) * 16 + q * 4 + r) * 64 + 3 * 16 + li] += acc3[r];
        }
    }
    __syncthreads();

    const int f  = tid & 63;
    const int ig = tid >> 6;   // 0..3
    #pragma unroll
    for (int cc = 0; cc < 4; ++cc) {
        const int i = cc * 4 + ig;
        const float v = red[(0 * 16 + i) * 64 + f] + red[(1 * 16 + i) * 64 + f];
        vpart[(size_t)(seg * NN + i0 + i) * FDIM + f] = v;
        if (f == 0) {
            const float zz = (zred[0][i] + zred[1][i]) + (zred[2][i] + zred[3][i]);
            zpart[seg * NN + i0 + i] = zz;
        }
    }
}

// Merge 8 segment partials: out = (sum v)/(sum z). 131072 float4.
__global__ __launch_bounds__(256) void gat_merge(
    const float* __restrict__ vpart, const float* __restrict__ zpart,
    float* __restrict__ out)
{
    const int g = blockIdx.x * 256 + threadIdx.x;
    const int row = g >> 4;
    float4 v = ((const float4*)vpart)[g];
    float z = zpart[row];
    #pragma unroll
    for (int k = 1; k < NSEG; ++k) {
        const float4 b = ((const float4*)vpart)[g + (size_t)k * NN * (FDIM / 4)];
        v.x += b.x; v.y += b.y; v.z += b.z; v.w += b.w;
        z += zpart[row + k * NN];
    }
    float4 o;
    o.x = v.x / z; o.y = v.y / z; o.z = v.z / z; o.w = v.w / z;
    ((float4*)out)[g] = o;
}

extern "C" void kernel_launch(void* const* d_in, const int* in_sizes, int n_in,
                              void* d_out, int out_size, void* d_ws, size_t ws_size,
                              hipStream_t stream) {
    const float* h   = (const float*)d_in[0];
    const int*   adj = (const int*)d_in[1];
    const float* W   = (const float*)d_in[2];
    const float* a   = (const float*)d_in[3];
    float* out = (float*)d_out;

    // ws: wfrag 1MB | fi 32K | fj 32K | vpart 16MB @2MB | zpart 256K @18MB
    unsigned short* wfrag = (unsigned short*)d_ws;
    float* fi = (float*)((char*)d_ws + (size_t)NN * FDIM * 2);
    float* fj = fi + NN;
    float* vpart = (float*)((char*)d_ws + (2u << 20));
    float* zpart = (float*)((char*)d_ws + (18u << 20));

    gat_phase1<<<NN / 16, 256, 0, stream>>>(h, W, a, wfrag, fi, fj);
    gat_fused<<<(NN / 16) * NSEG, 256, 0, stream>>>(adj, wfrag, fi, fj, vpart, zpart);
    gat_merge<<<NN * FDIM / 1024, 256, 0, stream>>>(vpart, zpart, out);
}